// Round 1
// baseline (502.047 us; speedup 1.0000x reference)
//
#include <hip/hip_runtime.h>
#include <stdint.h>

#define DEV static __device__ __forceinline__

typedef __attribute__((ext_vector_type(8))) short bf16x8;
typedef __attribute__((ext_vector_type(4))) float f32x4;

DEV unsigned short f2b(float f){
  union { float f; unsigned int u; } v; v.f = f;
  return (unsigned short)((v.u + 0x7FFFu + ((v.u >> 16) & 1u)) >> 16);
}

// ---------------- f32 -> bf16 convert ----------------
__global__ __launch_bounds__(256) void cvt_f32_bf16(const float* __restrict__ in,
                                                    unsigned short* __restrict__ out, int n4){
  int stride = gridDim.x * blockDim.x;
  for (int i = blockIdx.x * blockDim.x + threadIdx.x; i < n4; i += stride){
    float4 v = ((const float4*)in)[i];
    ushort4 o = make_ushort4(f2b(v.x), f2b(v.y), f2b(v.z), f2b(v.w));
    ((ushort4*)out)[i] = o;
  }
}

// ---------------- bt-GEMM: C[M,N] = A[M,K] * B[N,K]^T, 128x128 tile ----------------
// MODE 0: QKV gemm, fused RoPE epilogue -> Q,K,V [B,H,L,HD] bf16 (Q pre-scaled 1/8)
// MODE 1: proj gemm, f32 output [M,N]
template<int MODE>
__global__ __launch_bounds__(256, 2) void gemm_bt(
    const unsigned short* __restrict__ A,
    const unsigned short* __restrict__ Bw,
    int K, int nbn, int N,
    const float* __restrict__ cosp, const float* __restrict__ sinp,
    unsigned short* __restrict__ Qo, unsigned short* __restrict__ Ko,
    unsigned short* __restrict__ Vo, float* __restrict__ Cout)
{
  __shared__ __align__(16) unsigned char lds[32768]; // A tile @0 (16KB), B tile @16384
  const int t = threadIdx.x;
  const int wid = t >> 6, lane = t & 63;
  const int l15 = lane & 15, l4 = lane >> 4;
  const int bm = blockIdx.x / nbn, bn = blockIdx.x % nbn;
  const int m0 = bm * 128, n0 = bn * 128;
  const int mb = (wid >> 1) * 64, nb = (wid & 1) * 64;

  f32x4 acc[4][4];
  #pragma unroll
  for (int i = 0; i < 4; ++i)
    #pragma unroll
    for (int j = 0; j < 4; ++j)
      acc[i][j] = (f32x4){0.f, 0.f, 0.f, 0.f};

  for (int k0 = 0; k0 < K; k0 += 64){
    __syncthreads();
    #pragma unroll
    for (int i = 0; i < 4; ++i){
      int c = i * 256 + t;            // 0..1023 : 128 rows x 8 chunks(16B)
      int row = c >> 3, ch = c & 7;
      int sw = row * 128 + ((ch * 16) ^ ((row & 7) << 4));
      *(uint4*)(lds + sw)         = *(const uint4*)(A  + (size_t)(m0 + row) * K + k0 + ch * 8);
      *(uint4*)(lds + 16384 + sw) = *(const uint4*)(Bw + (size_t)(n0 + row) * K + k0 + ch * 8);
    }
    __syncthreads();
    #pragma unroll
    for (int ks = 0; ks < 2; ++ks){
      bf16x8 af[4], bfr[4];
      #pragma unroll
      for (int mi = 0; mi < 4; ++mi){
        int r = mb + mi * 16 + l15, ch = ks * 4 + l4;
        af[mi] = *(const bf16x8*)(lds + r * 128 + ((ch * 16) ^ ((r & 7) << 4)));
      }
      #pragma unroll
      for (int ni = 0; ni < 4; ++ni){
        int r = nb + ni * 16 + l15, ch = ks * 4 + l4;
        bfr[ni] = *(const bf16x8*)(lds + 16384 + r * 128 + ((ch * 16) ^ ((r & 7) << 4)));
      }
      #pragma unroll
      for (int mi = 0; mi < 4; ++mi)
        #pragma unroll
        for (int ni = 0; ni < 4; ++ni)
          acc[mi][ni] = __builtin_amdgcn_mfma_f32_16x16x32_bf16(af[mi], bfr[ni], acc[mi][ni], 0, 0, 0);
    }
  }

  if (MODE == 1){
    #pragma unroll
    for (int mi = 0; mi < 4; ++mi)
      #pragma unroll
      for (int ni = 0; ni < 4; ++ni)
        #pragma unroll
        for (int j = 0; j < 4; ++j){
          int m = m0 + mb + mi * 16 + l4 * 4 + j;
          int n = n0 + nb + ni * 16 + l15;
          Cout[(size_t)m * N + n] = acc[mi][ni][j];
        }
  } else {
    // RoPE epilogue. e in [0,6144): which = e>>11 (0=q,1=k,2=v), h=(e>>6)&31, d=e&63.
    // Wave spans 64 aligned cols => one head per wave; partner col d^32 lives in frag ni^2, same lane.
    #pragma unroll
    for (int ni = 0; ni < 4; ++ni){
      int e = n0 + nb + ni * 16 + l15;
      int which = e >> 11;
      int h = (e >> 6) & 31;
      int d = e & 63;
      unsigned short* dst = (which == 0) ? Qo : (which == 1) ? Ko : Vo;
      #pragma unroll
      for (int mi = 0; mi < 4; ++mi)
        #pragma unroll
        for (int j = 0; j < 4; ++j){
          int m = m0 + mb + mi * 16 + l4 * 4 + j;   // token index = b*2048 + l
          int b = m >> 11, l = m & 2047;
          float v = acc[mi][ni][j];
          float outv;
          if (which == 2){
            outv = v;
          } else {
            float pv = acc[mi][ni ^ 2][j];          // partner column d^32
            size_t ci = (size_t)(b * 2048 + l) * 64 + d;
            outv = v * cosp[ci] + ((d < 32) ? -pv : pv) * sinp[ci];
            if (which == 0) outv *= 0.125f;         // fold 1/sqrt(64)
          }
          dst[(size_t)((b * 32 + h) * 2048 + l) * 64 + d] = f2b(outv);
        }
    }
  }
}

// ---------------- V [BH, L, 64] -> Vt [BH, 64, L] ----------------
__global__ __launch_bounds__(256) void transpose_v(const unsigned short* __restrict__ V,
                                                   unsigned short* __restrict__ Vt){
  __shared__ unsigned short tile[64][72];
  int bh = blockIdx.x >> 5;
  int l0 = (blockIdx.x & 31) * 64;
  int t = threadIdx.x;
  #pragma unroll
  for (int i = 0; i < 2; ++i){
    int c = i * 256 + t;
    int row = c >> 3, ch = c & 7;
    uint4 v = *(const uint4*)(V + ((size_t)bh * 2048 + l0 + row) * 64 + ch * 8);
    const unsigned short* p = (const unsigned short*)&v;
    #pragma unroll
    for (int k = 0; k < 8; ++k) tile[row][ch * 8 + k] = p[k];
  }
  __syncthreads();
  #pragma unroll
  for (int i = 0; i < 2; ++i){
    int c = i * 256 + t;
    int drow = c >> 3, ch = c & 7;
    unsigned short tmp[8];
    #pragma unroll
    for (int k = 0; k < 8; ++k) tmp[k] = tile[ch * 8 + k][drow];
    *(uint4*)(Vt + ((size_t)bh * 64 + drow) * 2048 + l0 + ch * 8) = *(const uint4*)tmp;
  }
}

// ---------------- flash attention (causal), 4 independent waves x 32 q-rows ----------------
__global__ __launch_bounds__(256, 2) void attn_fwd(
    const unsigned short* __restrict__ Q, const unsigned short* __restrict__ K,
    const unsigned short* __restrict__ Vt, unsigned short* __restrict__ Y)
{
  __shared__ __align__(16) unsigned char plds[4][4096];  // per-wave P tile [32][64] bf16, swizzled
  int bh = blockIdx.x >> 4;
  int qt = 15 - (blockIdx.x & 15);      // heavy (late) q-tiles dispatched first
  int b = bh >> 5, h = bh & 31;
  int t = threadIdx.x, wid = t >> 6, lane = t & 63;
  int l15 = lane & 15, l4 = lane >> 4;
  int q0 = qt * 128 + wid * 32;
  const unsigned short* Qb = Q  + (size_t)bh * 2048 * 64;
  const unsigned short* Kb = K  + (size_t)bh * 2048 * 64;
  const unsigned short* Vb = Vt + (size_t)bh * 64 * 2048;
  unsigned char* myp = plds[wid];

  bf16x8 aq[2][2];
  #pragma unroll
  for (int mi = 0; mi < 2; ++mi)
    #pragma unroll
    for (int ks = 0; ks < 2; ++ks)
      aq[mi][ks] = *(const bf16x8*)(Qb + (size_t)(q0 + mi * 16 + l15) * 64 + ks * 32 + l4 * 8);

  f32x4 acc[2][4];
  #pragma unroll
  for (int mi = 0; mi < 2; ++mi)
    #pragma unroll
    for (int nd = 0; nd < 4; ++nd)
      acc[mi][nd] = (f32x4){0.f, 0.f, 0.f, 0.f};
  float mrow[2][4], lrow[2][4];
  #pragma unroll
  for (int mi = 0; mi < 2; ++mi)
    #pragma unroll
    for (int j = 0; j < 4; ++j){ mrow[mi][j] = -3e38f; lrow[mi][j] = 0.f; }

  int nkt = ((q0 + 31) >> 6) + 1;
  for (int kt = 0; kt < nkt; ++kt){
    int kv0 = kt * 64;
    f32x4 s[2][4];
    #pragma unroll
    for (int mi = 0; mi < 2; ++mi)
      #pragma unroll
      for (int ni = 0; ni < 4; ++ni)
        s[mi][ni] = (f32x4){0.f, 0.f, 0.f, 0.f};
    #pragma unroll
    for (int ks = 0; ks < 2; ++ks){
      bf16x8 bk[4];
      #pragma unroll
      for (int ni = 0; ni < 4; ++ni)
        bk[ni] = *(const bf16x8*)(Kb + (size_t)(kv0 + ni * 16 + l15) * 64 + ks * 32 + l4 * 8);
      #pragma unroll
      for (int mi = 0; mi < 2; ++mi)
        #pragma unroll
        for (int ni = 0; ni < 4; ++ni)
          s[mi][ni] = __builtin_amdgcn_mfma_f32_16x16x32_bf16(aq[mi][ks], bk[ni], s[mi][ni], 0, 0, 0);
    }
    if (kv0 + 63 > q0){   // causal mask only near the diagonal
      #pragma unroll
      for (int mi = 0; mi < 2; ++mi)
        #pragma unroll
        for (int ni = 0; ni < 4; ++ni)
          #pragma unroll
          for (int j = 0; j < 4; ++j){
            int q  = q0 + mi * 16 + l4 * 4 + j;
            int kv = kv0 + ni * 16 + l15;
            if (kv > q) s[mi][ni][j] = -1e30f;
          }
    }
    float pm[2][4], scl[2][4], rs[2][4];
    #pragma unroll
    for (int mi = 0; mi < 2; ++mi)
      #pragma unroll
      for (int j = 0; j < 4; ++j){
        float v = fmaxf(fmaxf(s[mi][0][j], s[mi][1][j]), fmaxf(s[mi][2][j], s[mi][3][j]));
        v = fmaxf(v, __shfl_xor(v, 1));
        v = fmaxf(v, __shfl_xor(v, 2));
        v = fmaxf(v, __shfl_xor(v, 4));
        v = fmaxf(v, __shfl_xor(v, 8));
        pm[mi][j] = v;
        float nm = fmaxf(mrow[mi][j], v);
        scl[mi][j] = __expf(mrow[mi][j] - nm);
        mrow[mi][j] = nm;
        rs[mi][j] = 0.f;
      }
    #pragma unroll
    for (int mi = 0; mi < 2; ++mi)
      #pragma unroll
      for (int ni = 0; ni < 4; ++ni)
        #pragma unroll
        for (int j = 0; j < 4; ++j){
          float p = __expf(s[mi][ni][j] - mrow[mi][j]);
          s[mi][ni][j] = p;
          rs[mi][j] += p;
        }
    #pragma unroll
    for (int mi = 0; mi < 2; ++mi)
      #pragma unroll
      for (int j = 0; j < 4; ++j){
        float v = rs[mi][j];
        v += __shfl_xor(v, 1); v += __shfl_xor(v, 2);
        v += __shfl_xor(v, 4); v += __shfl_xor(v, 8);
        lrow[mi][j] = lrow[mi][j] * scl[mi][j] + v;
      }
    #pragma unroll
    for (int mi = 0; mi < 2; ++mi)
      #pragma unroll
      for (int nd = 0; nd < 4; ++nd)
        #pragma unroll
        for (int j = 0; j < 4; ++j)
          acc[mi][nd][j] *= scl[mi][j];
    // P (C-layout) -> LDS (swizzled) so it can be re-read in A-fragment layout
    #pragma unroll
    for (int mi = 0; mi < 2; ++mi)
      #pragma unroll
      for (int ni = 0; ni < 4; ++ni)
        #pragma unroll
        for (int j = 0; j < 4; ++j){
          int r = mi * 16 + l4 * 4 + j, c = ni * 16 + l15;
          *(unsigned short*)(myp + r * 128 + ((c * 2) ^ ((r & 7) << 4))) = f2b(s[mi][ni][j]);
        }
    __threadfence_block();   // wave-local LDS ordering (no cross-wave deps; loops are divergent)
    #pragma unroll
    for (int ks2 = 0; ks2 < 2; ++ks2){
      bf16x8 ap[2], bv[4];
      #pragma unroll
      for (int mi = 0; mi < 2; ++mi){
        int r = mi * 16 + l15, ch = ks2 * 4 + l4;
        ap[mi] = *(const bf16x8*)(myp + r * 128 + ((ch * 16) ^ ((r & 7) << 4)));
      }
      #pragma unroll
      for (int nd = 0; nd < 4; ++nd)
        bv[nd] = *(const bf16x8*)(Vb + (size_t)(nd * 16 + l15) * 2048 + kv0 + ks2 * 32 + l4 * 8);
      #pragma unroll
      for (int mi = 0; mi < 2; ++mi)
        #pragma unroll
        for (int nd = 0; nd < 4; ++nd)
          acc[mi][nd] = __builtin_amdgcn_mfma_f32_16x16x32_bf16(ap[mi], bv[nd], acc[mi][nd], 0, 0, 0);
    }
  }
  #pragma unroll
  for (int mi = 0; mi < 2; ++mi)
    #pragma unroll
    for (int nd = 0; nd < 4; ++nd)
      #pragma unroll
      for (int j = 0; j < 4; ++j){
        int q = q0 + mi * 16 + l4 * 4 + j;
        int d = nd * 16 + l15;
        float o = acc[mi][nd][j] / lrow[mi][j];
        Y[(size_t)(b * 2048 + q) * 2048 + h * 64 + d] = f2b(o);
      }
}

// ---------------- launch ----------------
extern "C" void kernel_launch(void* const* d_in, const int* in_sizes, int n_in,
                              void* d_out, int out_size, void* d_ws, size_t ws_size,
                              hipStream_t stream){
  (void)in_sizes; (void)n_in; (void)out_size; (void)ws_size;
  const float* x     = (const float*)d_in[0];
  const float* cosp  = (const float*)d_in[1];
  const float* sinp  = (const float*)d_in[2];
  const float* Wqkv  = (const float*)d_in[3];
  const float* Wproj = (const float*)d_in[4];
  float* out = (float*)d_out;
  char* ws = (char*)d_ws;

  // workspace layout (96 MiB, with aliasing):
  // [0,16M)   Xb  (bf16 x)            -> reused as Vt after GEMM1
  // [16,40M)  Wqkvb
  // [40,48M)  Wprojb
  // [48,64M)  Q   [64,80M) K   [80,96M) V -> reused as Y after transpose
  unsigned short* Xb  = (unsigned short*)(ws);
  unsigned short* Wqb = (unsigned short*)(ws + 16777216);
  unsigned short* Wpb = (unsigned short*)(ws + 41943040);
  unsigned short* Qb  = (unsigned short*)(ws + 50331648);
  unsigned short* Kb  = (unsigned short*)(ws + 67108864);
  unsigned short* Vb  = (unsigned short*)(ws + 83886080);
  unsigned short* Vtb = Xb;   // alias: Xb dead after GEMM1
  unsigned short* Yb  = Vb;   // alias: V dead after transpose

  cvt_f32_bf16<<<1536, 256, 0, stream>>>(x,     Xb,  2097152);  // 8.39M elems
  cvt_f32_bf16<<<1536, 256, 0, stream>>>(Wqkv,  Wqb, 3145728);  // 12.58M
  cvt_f32_bf16<<<1536, 256, 0, stream>>>(Wproj, Wpb, 1048576);  // 4.19M

  // QKV GEMM + RoPE: M=4096, N=6144, K=2048
  gemm_bt<0><<<32 * 48, 256, 0, stream>>>(Xb, Wqb, 2048, 48, 6144,
                                          cosp, sinp, Qb, Kb, Vb, nullptr);
  transpose_v<<<2048, 256, 0, stream>>>(Vb, Vtb);
  attn_fwd<<<1024, 256, 0, stream>>>(Qb, Kb, Vtb, Yb);
  // out proj: M=4096, N=2048, K=2048, f32 out
  gemm_bt<1><<<32 * 16, 256, 0, stream>>>(Yb, Wpb, 2048, 16, 2048,
                                          nullptr, nullptr, nullptr, nullptr, nullptr, out);
}